// Round 3
// baseline (156.242 us; speedup 1.0000x reference)
//
#include <hip/hip_runtime.h>

// LayerHypercube: out[b, f*1024+o] = sum_j x[b, o^(1<<j)] * w[f,j,o] + bias[f,o] + x[b,o]
// B=2048, F=16, O=I=1024, BITS=10. fm analytic (o^(1<<j)) -- not read.
//
// R6 = R5 with the compile fix: __builtin_nontemporal_store requires a NATIVE
// clang vector (ext_vector_type), not HIP's float4 class. Logic unchanged.
//
// Theory (from R5): the ~70 us kernel (dur 155 - ~85 us timed poison fill) is
// issue/latency-bound: 128 scalar stores (256 B/wave-instr @ 4 KB stride) + 176
// scalar ds_reads per thread. Restructure to float4 granularity: each thread
// owns 4 consecutive o, 2 f per wave (weights still 80 VGPR). Stores become 16
// dwordx4 (1 KB/wave-instr, /4 instr count); gathers j=0,1 (o^1,o^2) are
// in-register component swizzles; j=2..7 are ds_read_b128 lane permutations
// (conflict-free); j=8,9 read slots oc^1, oc^2. Staging amplification 5x -> 3x.
//
// Block: 256 thr = 4 waves x 2f = 8 f  (fblk picks f 0-7 / 8-15), o-span 256,
// BTILE=8 rows. LDS 24 KB = [8 rows][3 slots][256 floats]. Grid 2048 blocks.
// Swizzle: all 8 (oc,fblk) blocks of a btile-group on one XCD (x+w fit its L2).

#define BTILE 8

typedef float fx4 __attribute__((ext_vector_type(4)));

__global__ __launch_bounds__(256, 3) void hypercube_kernel(
    const float* __restrict__ x,      // [2048][1024]
    const float* __restrict__ w,      // [16][10][1024]
    const float* __restrict__ bias,   // [16][1024]
    float* __restrict__ out)          // [2048][16*1024]
{
    __shared__ float xs[BTILE * 3 * 256];   // 24 KB: [row][slot][256]

    const int tid  = threadIdx.x;
    const int lane = tid & 63;
    const int wave = tid >> 6;          // 0..3

    // Bijective XCD-group swizzle: 2048 blocks = 8 XCD x 32 btile x (4 oc x 2 fblk).
    const int bid   = blockIdx.x;
    const int xcd   = bid & 7;
    const int ix    = bid >> 3;         // 0..255
    const int btile = xcd * 32 + (ix >> 3);
    const int sub   = ix & 7;
    const int oc    = sub >> 1;         // 0..3: which 256-wide o-chunk
    const int fblk  = sub & 1;          // 0..1: which 8 feature maps

    const int b0    = btile * BTILE;
    const int obase = oc * 256;

    // ---- Stage 8 rows x 3 slots x 256 floats (1536 float4, 6 per thread) ----
    // slot s holds o-chunk oc^s (s=0:self, 1:^256, 2:^512). 1 KB contiguous
    // per wave load instruction.
    #pragma unroll
    for (int it = 0; it < 6; ++it) {
        const int q    = it * 256 + tid;     // float4 index, 0..1535
        const int row  = q / 192;            // 192 float4 per row
        const int rem  = q - row * 192;
        const int slot = rem >> 6;           // 64 float4 per slot
        const int col  = (rem & 63) << 2;
        const fx4 v = *(const fx4*)&x[(size_t)(b0 + row) * 1024 + (oc ^ slot) * 256 + col];
        *(fx4*)&xs[q * 4] = v;
    }

    // ---- Weights: 2 f per wave, 4 o per lane -> 80 VGPR, float4 loads ----
    const int fw0 = fblk * 8 + wave * 2;
    float wr[2][10][4], br[2][4];
    #pragma unroll
    for (int ff = 0; ff < 2; ++ff) {
        #pragma unroll
        for (int j = 0; j < 10; ++j)
            *(fx4*)wr[ff][j] = *(const fx4*)&w[(size_t)((fw0 + ff) * 10 + j) * 1024 + obase + lane * 4];
        *(fx4*)br[ff] = *(const fx4*)&bias[(size_t)(fw0 + ff) * 1024 + obase + lane * 4];
    }

    __syncthreads();

    // ---- Compute: 9 ds_read_b128 + 88 FMA + 2 dwordx4 NT stores per row ----
    for (int row = 0; row < BTILE; ++row) {
        const float* __restrict__ xr = &xs[row * 768];
        float v0[4], v4[4], v8[4], v16[4], v32[4], v64[4], v128[4], v256[4], v512[4];
        *(fx4*)v0   = *(const fx4*)&xr[lane * 4];          // own o's (also j=0,1 src)
        *(fx4*)v4   = *(const fx4*)&xr[(lane ^ 1)  * 4];   // o ^ 4
        *(fx4*)v8   = *(const fx4*)&xr[(lane ^ 2)  * 4];   // o ^ 8
        *(fx4*)v16  = *(const fx4*)&xr[(lane ^ 4)  * 4];   // o ^ 16
        *(fx4*)v32  = *(const fx4*)&xr[(lane ^ 8)  * 4];   // o ^ 32
        *(fx4*)v64  = *(const fx4*)&xr[(lane ^ 16) * 4];   // o ^ 64
        *(fx4*)v128 = *(const fx4*)&xr[(lane ^ 32) * 4];   // o ^ 128
        *(fx4*)v256 = *(const fx4*)&xr[256 + lane * 4];    // o ^ 256 (slot 1)
        *(fx4*)v512 = *(const fx4*)&xr[512 + lane * 4];    // o ^ 512 (slot 2)

        float* __restrict__ ob = out + (size_t)(b0 + row) * 16384 + obase + lane * 4;
        #pragma unroll
        for (int ff = 0; ff < 2; ++ff) {
            fx4 av;
            #pragma unroll
            for (int k = 0; k < 4; ++k) {
                float a = br[ff][k] + v0[k];          // bias + tiled-x term
                a = fmaf(v0[k ^ 1], wr[ff][0][k], a); // j=0: o^1 in-register
                a = fmaf(v0[k ^ 2], wr[ff][1][k], a); // j=1: o^2 in-register
                a = fmaf(v4[k],     wr[ff][2][k], a);
                a = fmaf(v8[k],     wr[ff][3][k], a);
                a = fmaf(v16[k],    wr[ff][4][k], a);
                a = fmaf(v32[k],    wr[ff][5][k], a);
                a = fmaf(v64[k],    wr[ff][6][k], a);
                a = fmaf(v128[k],   wr[ff][7][k], a);
                a = fmaf(v256[k],   wr[ff][8][k], a);
                a = fmaf(v512[k],   wr[ff][9][k], a);
                av[k] = a;
            }
            __builtin_nontemporal_store(av, (fx4*)&ob[(fw0 + ff) * 1024]); // 1 KB/wave-instr
        }
    }
}

extern "C" void kernel_launch(void* const* d_in, const int* in_sizes, int n_in,
                              void* d_out, int out_size, void* d_ws, size_t ws_size,
                              hipStream_t stream) {
    const float* x    = (const float*)d_in[0];
    const float* w    = (const float*)d_in[1];
    const float* bias = (const float*)d_in[2];
    // d_in[3] = fm (int32) -- analytic, unused.
    float* out = (float*)d_out;

    dim3 grid(2048);                  // 8 XCD x 32 btile-groups x 4 oc x 2 fblk
    dim3 block(256);                  // 4 waves x 2 f
    hypercube_kernel<<<grid, block, 0, stream>>>(x, w, bias, out);
}